// Round 21
// baseline (50.723 us; speedup 1.0000x reference)
//
#include <hip/hip_runtime.h>

#define B_ 8192
#define T_ 128
#define I_ 28
#define H_ 64
#define O_ 10
#define HS 72        // ushort stride per batch-row in h buffer (144 B, 16B-aligned)
#define XSW 512      // ushorts per x slot: 16 rows x 32 bf16 (1 KB)

typedef __attribute__((ext_vector_type(8))) short bf16x8;
typedef __attribute__((ext_vector_type(4))) float f32x4;
typedef __attribute__((ext_vector_type(4))) unsigned int u32x4;

__device__ __forceinline__ unsigned short f2bf(float f) {
    unsigned int u = __builtin_bit_cast(unsigned int, f);
    u += 0x7fffu + ((u >> 16) & 1u);   // RNE
    return (unsigned short)(u >> 16);
}
__device__ __forceinline__ unsigned int cvtpk(float lo, float hi) {
    unsigned int r;
    asm("v_cvt_pk_bf16_f32 %0, %1, %2" : "=v"(r) : "v"(lo), "v"(hi));
    return r;
}
__device__ __forceinline__ bf16x8 mkfrag(unsigned int a, unsigned int b,
                                         unsigned int c, unsigned int d) {
    u32x4 u = {a, b, c, d};
    return __builtin_bit_cast(bf16x8, u);
}
__device__ __forceinline__ float exp2f_fast(float x) {
#if __has_builtin(__builtin_amdgcn_exp2f)
    return __builtin_amdgcn_exp2f(x);
#else
    return __expf(x * 0.6931471805599453f);
#endif
}
// tanh pair -> packed bf16x2. tanh(x)=1-2/(1+2^(2*log2e*x)); saturates at +-1.
__device__ __forceinline__ unsigned int tanh2_bf(float xa, float xb) {
    float ta = exp2f_fast(xa * 2.885390081777927f);
    float tb = exp2f_fast(xb * 2.885390081777927f);
    float ra = __builtin_amdgcn_rcpf(1.0f + ta);
    float rb = __builtin_amdgcn_rcpf(1.0f + tb);
    return cvtpk(fmaf(-2.0f, ra, 1.0f), fmaf(-2.0f, rb, 1.0f));
}

#define MFMA(A, B, C) __builtin_amdgcn_mfma_f32_16x16x32_bf16((A), (B), (C), 0, 0, 0)

__launch_bounds__(256, 1)
__global__ void rnn_split_kernel(const float* __restrict__ x,
                                 const float* __restrict__ W_ih,
                                 const float* __restrict__ W_hh,
                                 const float* __restrict__ b_ih,
                                 const float* __restrict__ b_hh,
                                 const float* __restrict__ W_out,
                                 const float* __restrict__ b_out,
                                 float* __restrict__ out) {
    __shared__ __align__(16) unsigned short xsb[8][XSW];   // x slots, bf16
    __shared__ __align__(16) unsigned short hb[2][16 * HS];

    const int tid = threadIdx.x;
    const int lane = tid & 63;
    const int w = tid >> 6;           // wave id == output tile (h cols, permuted)
    const int m = lane & 15;          // batch row within tile
    const int g = lane >> 4;          // k-group
    const int b0 = blockIdx.x * 16;
    const int row = b0 + m;

    // Swapped-operand MFMA + permuted-W (verified R3/R5-R20), H split 4 ways:
    // wave w computes h-cols n_phys(w,i)=8*(i>>2)+4*(w&1)+(i&3)+32*(w>>1).
    // Lane(g,m) reg r yields n=8g+4(w&1)+r+32(w>>1): 4 CONTIGUOUS cols ->
    // one b64 LDS write; every wave then b128-reads its full-H B-fragments.
    bf16x8 wih, whhA, whhB;
    f32x4 biasC;
    {
        const int nA = 8 * (m >> 2) + 4 * (w & 1) + (m & 3) + 32 * (w >> 1);
#pragma unroll
        for (int j = 0; j < 8; ++j) {
            const int k = 8 * g + j;
            wih[j]  = (k < I_) ? (short)f2bf(W_ih[nA * I_ + k]) : (short)0;
            whhA[j] = (short)f2bf(W_hh[nA * H_ + k]);
            whhB[j] = (short)f2bf(W_hh[nA * H_ + 32 + k]);
        }
#pragma unroll
        for (int r = 0; r < 4; ++r) {
            const int nb = 8 * g + 4 * (w & 1) + r + 32 * (w >> 1);
            biasC[r] = b_ih[nb] + b_hh[nb];
        }
    }
    const int wbase = m * HS + 8 * g + 4 * (w & 1) + 32 * (w >> 1);  // h write (ushorts)
    const int rbase = m * HS + 8 * g;                                 // h frag read

    // ---- x staging (bf16-in-LDS): slot s = x[t], t===s (mod 8), layout
    // [16 rows][32 bf16] (28 data + 4 pad; pad cols hit zero weights).
    // ONLY wave 0 stages: per slot, lane l loads x[row=l>>2][c=(l&3)*8 .. +7]
    // as 2x float4, cvtpk's to 4 words, writes ONE b128 at ushort 8*l.
    // Loads are issued 2 barriers (~1300 cyc) before their LDS write, pinned
    // by the in-loop s_barrier memory clobber -- no vmcnt discipline needed.
    // Consumers read their full fragment as ONE b128 (no cvt).
    const int sr = lane >> 2;          // staging row
    const int sc = (lane & 3) * 8;     // staging col base
    const float* pw0 = x + (size_t)(b0 + sr) * (T_ * I_) + sc;
    // c==24: second chunk would be cols 28..31 (past row end) -> dup 24..27
    const float* pw1 = pw0 + ((sc == 24) ? 0 : 4);
    unsigned short* sdst = &xsb[0][0];   // slot s dest: sdst + s*XSW + 8*lane

#define SLOAD(A0, A1, tt) do {                                               \
        const int tc_ = ((tt) < T_) ? (tt) : (T_ - 1);                       \
        A0 = *reinterpret_cast<const float4*>(pw0 + tc_ * I_);               \
        A1 = *reinterpret_cast<const float4*>(pw1 + tc_ * I_);               \
    } while (0)

#define SWRITE(s, A0, A1) do {                                               \
        u32x4 v_;                                                            \
        v_[0] = cvtpk(A0.x, A0.y); v_[1] = cvtpk(A0.z, A0.w);                \
        v_[2] = cvtpk(A1.x, A1.y); v_[3] = cvtpk(A1.z, A1.w);                \
        *reinterpret_cast<u32x4*>(sdst + (s) * XSW + 8 * lane) = v_;         \
    } while (0)

    // Prologue staging: slots 0..7 <- x[0..7], two rounds of 4 (VGPR cap).
    if (w == 0) {
        float4 a0, a1, b0v, b1, c0, c1, d0, d1;
        SLOAD(a0, a1, 0); SLOAD(b0v, b1, 1); SLOAD(c0, c1, 2); SLOAD(d0, d1, 3);
        SWRITE(0, a0, a1); SWRITE(1, b0v, b1); SWRITE(2, c0, c1); SWRITE(3, d0, d1);
        SLOAD(a0, a1, 4); SLOAD(b0v, b1, 5); SLOAD(c0, c1, 6); SLOAD(d0, d1, 7);
        SWRITE(4, a0, a1); SWRITE(5, b0v, b1); SWRITE(6, c0, c1); SWRITE(7, d0, d1);
    }
    asm volatile("s_waitcnt lgkmcnt(0) vmcnt(0)\n\ts_barrier" ::: "memory");

    // steady-state staging regs: setA/setB ping-pong, distance 2 steps
    float4 sA0, sA1, sB0, sB1;
    if (w == 0) { SLOAD(sA0, sA1, 8); SLOAD(sB0, sB1, 9); }

    // consumer fragment offset (ushorts): row m, cols 8g..8g+7
    const int xoffB = m * 32 + g * 8;

    f32x4 pxA, pxB;   // px pipelined ONE step ahead (off-chain)
    {
        bf16x8 xf0 = *reinterpret_cast<const bf16x8*>(&xsb[0][xoffB]);
        pxA = MFMA(wih, xf0, biasC);          // px(t=0)
    }
    bf16x8 h0f = mkfrag(0, 0, 0, 0), h1f = mkfrag(0, 0, 0, 0);

    // Body for time t (u=t%8, PXC=px(t), PXN=px(t+1) out) -- R20 rec-first
    // order; staging: w0 writes slot u <- x[t+8] (regs loaded at step t-2),
    // reloads that set <- x[t+10].
#define STEP(u, TB, PXC, PXN, S0, S1) do {                                    \
        f32x4 aA = MFMA(whhA, h0f, PXC);                                      \
        aA = MFMA(whhB, h1f, aA);                                             \
        bf16x8 xf = *reinterpret_cast<const bf16x8*>(                         \
            &xsb[((u) + 1) & 7][xoffB]);                                      \
        PXN = MFMA(wih, xf, biasC);                                           \
        const unsigned int p0 = tanh2_bf(aA[0], aA[1]);                       \
        const unsigned int p1 = tanh2_bf(aA[2], aA[3]);                       \
        uint2 pv; pv.x = p0; pv.y = p1;                                       \
        *reinterpret_cast<uint2*>(&hb[((u) + 1) & 1][wbase]) = pv;            \
        if (w == 0) {                                                         \
            SWRITE((u), S0, S1);                                              \
            SLOAD(S0, S1, (TB) + (u) + 10);                                   \
        }                                                                     \
        asm volatile("s_waitcnt lgkmcnt(0)\n\ts_barrier" ::: "memory");       \
        h0f = *reinterpret_cast<const bf16x8*>(&hb[((u) + 1) & 1][rbase]);    \
        h1f = *reinterpret_cast<const bf16x8*>(&hb[((u) + 1) & 1][rbase + 32]); \
    } while (0)

    for (int tb = 0; tb < T_; tb += 8) {
        STEP(0, tb, pxA, pxB, sA0, sA1); STEP(1, tb, pxB, pxA, sB0, sB1);
        STEP(2, tb, pxA, pxB, sA0, sA1); STEP(3, tb, pxB, pxA, sB0, sB1);
        STEP(4, tb, pxA, pxB, sA0, sA1); STEP(5, tb, pxB, pxA, sB0, sB1);
        STEP(6, tb, pxA, pxB, sA0, sA1); STEP(7, tb, pxB, pxA, sB0, sB1);
    }
#undef STEP
#undef SWRITE
#undef SLOAD

    // ---- epilogue: out[row][o] = h_last . W_out[o] + b_out[o] ----
    // All waves hold identical h_last frags; wave 0 does the output.
    if (w == 0) {
        float hf[16];
        {
            u32x4 H0 = __builtin_bit_cast(u32x4, h0f);
            u32x4 H1 = __builtin_bit_cast(u32x4, h1f);
#pragma unroll
            for (int p = 0; p < 4; ++p) {
                hf[2 * p]     = __builtin_bit_cast(float, H0[p] << 16);
                hf[2 * p + 1] = __builtin_bit_cast(float, H0[p] & 0xffff0000u);
                hf[8 + 2 * p]     = __builtin_bit_cast(float, H1[p] << 16);
                hf[8 + 2 * p + 1] = __builtin_bit_cast(float, H1[p] & 0xffff0000u);
            }
        }
        float pacc[O_];
#pragma unroll
        for (int o = 0; o < O_; ++o) {
            const float* wo = W_out + o * H_;
            float4 wA = *reinterpret_cast<const float4*>(wo + 8 * g);
            float4 wB = *reinterpret_cast<const float4*>(wo + 8 * g + 4);
            float4 wC = *reinterpret_cast<const float4*>(wo + 32 + 8 * g);
            float4 wD = *reinterpret_cast<const float4*>(wo + 32 + 8 * g + 4);
            float s = hf[0] * wA.x + hf[1] * wA.y + hf[2] * wA.z + hf[3] * wA.w
                    + hf[4] * wB.x + hf[5] * wB.y + hf[6] * wB.z + hf[7] * wB.w
                    + hf[8] * wC.x + hf[9] * wC.y + hf[10] * wC.z + hf[11] * wC.w
                    + hf[12] * wD.x + hf[13] * wD.y + hf[14] * wD.z + hf[15] * wD.w;
            s += __shfl_xor(s, 16);
            s += __shfl_xor(s, 32);
            pacc[o] = s;
        }
        if (g == 0) {
#pragma unroll
            for (int o = 0; o < O_; ++o)
                out[(size_t)row * O_ + o] = pacc[o] + b_out[o];
        }
    }
}

extern "C" void kernel_launch(void* const* d_in, const int* in_sizes, int n_in,
                              void* d_out, int out_size, void* d_ws, size_t ws_size,
                              hipStream_t stream) {
    const float* x     = (const float*)d_in[0];
    const float* W_ih  = (const float*)d_in[1];
    const float* W_hh  = (const float*)d_in[2];
    const float* b_ih  = (const float*)d_in[3];
    const float* b_hh  = (const float*)d_in[4];
    const float* W_out = (const float*)d_in[5];
    const float* b_out = (const float*)d_in[6];
    float* out = (float*)d_out;

    dim3 grid(B_ / 16);
    dim3 block(256);
    rnn_split_kernel<<<grid, block, 0, stream>>>(x, W_ih, W_hh, b_ih, b_hh,
                                                 W_out, b_out, out);
}

// Round 22
// 47.311 us; speedup vs baseline: 1.0721x; 1.0721x over previous
//
#include <hip/hip_runtime.h>

#define B_ 8192
#define T_ 128
#define I_ 28
#define H_ 64
#define O_ 10
#define RING 8
#define SLOTF 512   // floats per x-ring slot: 448 data + 64 pad
#define HS 72       // ushort stride per batch-row in h buffer (144 B, 16B-aligned)

typedef __attribute__((ext_vector_type(8))) short bf16x8;
typedef __attribute__((ext_vector_type(4))) float f32x4;
typedef __attribute__((ext_vector_type(4))) unsigned int u32x4;

__device__ __forceinline__ unsigned short f2bf(float f) {
    unsigned int u = __builtin_bit_cast(unsigned int, f);
    u += 0x7fffu + ((u >> 16) & 1u);   // RNE
    return (unsigned short)(u >> 16);
}
__device__ __forceinline__ unsigned int cvtpk(float lo, float hi) {
    unsigned int r;
    asm("v_cvt_pk_bf16_f32 %0, %1, %2" : "=v"(r) : "v"(lo), "v"(hi));
    return r;
}
__device__ __forceinline__ bf16x8 mkfrag(unsigned int a, unsigned int b,
                                         unsigned int c, unsigned int d) {
    u32x4 u = {a, b, c, d};
    return __builtin_bit_cast(bf16x8, u);
}
__device__ __forceinline__ float exp2f_fast(float x) {
#if __has_builtin(__builtin_amdgcn_exp2f)
    return __builtin_amdgcn_exp2f(x);
#else
    return __expf(x * 0.6931471805599453f);
#endif
}
// tanh pair -> packed bf16x2, MERGED-RCP: tanh(x)=1-2/(1+2^(2*log2e*x));
// one v_rcp for both values (1/da = db*rcp(da*db)). 3 trans/pair (was 4).
// Plain scalar ops -- compiler schedules freely (R7 lesson).
__device__ __forceinline__ unsigned int tanh2_bf(float xa, float xb) {
    float ta = exp2f_fast(xa * 2.885390081777927f);
    float tb = exp2f_fast(xb * 2.885390081777927f);
    float da = 1.0f + ta, db = 1.0f + tb;
    float R = __builtin_amdgcn_rcpf(da * db);
    float ra = db * R;   // = 1/da
    float rb = da * R;   // = 1/db
    return cvtpk(fmaf(-2.0f, ra, 1.0f), fmaf(-2.0f, rb, 1.0f));
}

// async global->LDS: no VGPR destination (no regalloc hazard); counted by vmcnt
__device__ __forceinline__ void gload_lds(const float* g, float* l) {
    __builtin_amdgcn_global_load_lds(
        (const __attribute__((address_space(1))) unsigned int*)g,
        (__attribute__((address_space(3))) unsigned int*)l, 16, 0, 0);
}

#define MFMA(A, B, C) __builtin_amdgcn_mfma_f32_16x16x32_bf16((A), (B), (C), 0, 0, 0)

__launch_bounds__(256, 1)
__global__ void rnn_split_kernel(const float* __restrict__ x,
                                 const float* __restrict__ W_ih,
                                 const float* __restrict__ W_hh,
                                 const float* __restrict__ b_ih,
                                 const float* __restrict__ b_hh,
                                 const float* __restrict__ W_out,
                                 const float* __restrict__ b_out,
                                 float* __restrict__ out) {
    __shared__ __align__(16) float xs[RING][SLOTF];
    __shared__ __align__(16) unsigned short hb[2][16 * HS];

    const int tid = threadIdx.x;
    const int lane = tid & 63;
    const int w = tid >> 6;           // wave id == output tile (h cols, permuted)
    const int m = lane & 15;          // batch row within tile
    const int g = lane >> 4;          // k-group
    const int b0 = blockIdx.x * 16;
    const int row = b0 + m;

    // Swapped-operand MFMA + permuted-W (verified R3/R5-R21), H split 4 ways:
    // wave w computes h-cols n_phys(w,i)=8*(i>>2)+4*(w&1)+(i&3)+32*(w>>1).
    // Lane(g,m) reg r yields n=8g+4(w&1)+r+32(w>>1): 4 CONTIGUOUS cols ->
    // one b64 LDS write; every wave then b128-reads its full-H B-fragments.
    bf16x8 wih, whhA, whhB;
    f32x4 biasC;
    {
        const int nA = 8 * (m >> 2) + 4 * (w & 1) + (m & 3) + 32 * (w >> 1);
#pragma unroll
        for (int j = 0; j < 8; ++j) {
            const int k = 8 * g + j;
            wih[j]  = (k < I_) ? (short)f2bf(W_ih[nA * I_ + k]) : (short)0;
            whhA[j] = (short)f2bf(W_hh[nA * H_ + k]);
            whhB[j] = (short)f2bf(W_hh[nA * H_ + 32 + k]);
        }
#pragma unroll
        for (int r = 0; r < 4; ++r) {
            const int nb = 8 * g + 4 * (w & 1) + r + 32 * (w >> 1);
            biasC[r] = b_ih[nb] + b_hh[nb];
        }
    }
    const int wbase = m * HS + 8 * g + 4 * (w & 1) + 32 * (w >> 1);  // h write (ushorts)
    const int rbase = m * HS + 8 * g;                                 // h frag read

    // ---- x staging: slot = 16 rows x 112B (7 x 16B chunks/row). ONLY wave 0
    // issues DMA; other waves inherit completion via w0's vmcnt + s_barrier.
    const int cA = lane;
    const int cB = (64 + lane <= 111) ? (64 + lane) : 111;
    const float* gA = x + (size_t)(b0 + cA / 7) * (T_ * I_) + (cA % 7) * 4;
    const float* gB = x + (size_t)(b0 + cB / 7) * (T_ * I_) + (cB % 7) * 4;

#define ISSUE(s, tt) do {                                                    \
        const int tc_ = ((tt) < T_) ? (tt) : (T_ - 1);                       \
        gload_lds(gA + (size_t)tc_ * I_, &xs[s][0]);                         \
        gload_lds(gB + (size_t)tc_ * I_, &xs[s][256]);                       \
    } while (0)

    const int xoff = m * 28 + g * 8;
    const int hoff = (g < 3) ? 4 : 0;   // g==3 hi half = k 28..31 (zero weights)

    // Drain setup VMEM so w0's vmcnt counts only staging DMA from here on.
    __builtin_amdgcn_sched_barrier(0);
    asm volatile("s_waitcnt vmcnt(0)" ::: "memory");
    __builtin_amdgcn_sched_barrier(0);

    if (w == 0) {
        ISSUE(0, 0); ISSUE(1, 1); ISSUE(2, 2); ISSUE(3, 3);
        ISSUE(4, 4); ISSUE(5, 5); ISSUE(6, 6); ISSUE(7, 7);
        // slots 0,1,2 landed when <=10 of the 16 remain outstanding
        asm volatile("s_waitcnt vmcnt(10)" ::: "memory");
    }
    asm volatile("s_barrier" ::: "memory");   // publish x slots 0..2

    // px pipelined TWO steps ahead: px(t) consumed and px(t+2) produced into
    // the SAME register each step; A/B alternate (period 2).
    f32x4 pxA, pxB;
    {
        const f32x4 l0 = *reinterpret_cast<const f32x4*>(&xs[0][xoff]);
        const f32x4 h0v = *reinterpret_cast<const f32x4*>(&xs[0][xoff + hoff]);
        bf16x8 xf0 = mkfrag(cvtpk(l0[0], l0[1]), cvtpk(l0[2], l0[3]),
                            cvtpk(h0v[0], h0v[1]), cvtpk(h0v[2], h0v[3]));
        pxA = MFMA(wih, xf0, biasC);          // px(0)
        const f32x4 l1 = *reinterpret_cast<const f32x4*>(&xs[1][xoff]);
        const f32x4 h1v = *reinterpret_cast<const f32x4*>(&xs[1][xoff + hoff]);
        bf16x8 xf1 = mkfrag(cvtpk(l1[0], l1[1]), cvtpk(l1[2], l1[3]),
                            cvtpk(h1v[0], h1v[1]), cvtpk(h1v[2], h1v[3]));
        pxB = MFMA(wih, xf1, biasC);          // px(1)
    }
    bf16x8 h0f = mkfrag(0, 0, 0, 0), h1f = mkfrag(0, 0, 0, 0);

    // Body for time t (u=t%8; PX consumed=px(t), overwritten with px(t+2)):
    //   1. x ds_reads for slot t+2 ISSUE (raw loads; slot guaranteed by step
    //      t-1's vmcnt(10))
    //   2. chained recA->recB (wait lgkmcnt(2): h done, x outstanding)
    //   3. cvtpk + px-MFMA(t+2) -- x lgkm satisfied under rec shadow
    //   4. tanh -> b64 h-write; w0 DMA slot u <- x[t+8] + vmcnt(10)
    //   5. lgkm-drain + barrier; h-read(t+1) issue
#define STEP(u, TB, PX) do {                                                  \
        const f32x4 xlo_ = *reinterpret_cast<const f32x4*>(                   \
            &xs[((u) + 2) & 7][xoff]);                                        \
        const f32x4 xhi_ = *reinterpret_cast<const f32x4*>(                   \
            &xs[((u) + 2) & 7][xoff + hoff]);                                 \
        f32x4 aA = MFMA(whhA, h0f, PX);                                       \
        aA = MFMA(whhB, h1f, aA);                                             \
        bf16x8 xf = mkfrag(cvtpk(xlo_[0], xlo_[1]), cvtpk(xlo_[2], xlo_[3]),  \
                           cvtpk(xhi_[0], xhi_[1]), cvtpk(xhi_[2], xhi_[3])); \
        PX = MFMA(wih, xf, biasC);                                            \
        const unsigned int p0 = tanh2_bf(aA[0], aA[1]);                       \
        const unsigned int p1 = tanh2_bf(aA[2], aA[3]);                       \
        uint2 pv; pv.x = p0; pv.y = p1;                                       \
        *reinterpret_cast<uint2*>(&hb[((u) + 1) & 1][wbase]) = pv;            \
        if (w == 0) {                                                         \
            ISSUE((u), (TB) + (u) + 8);                                       \
            asm volatile("s_waitcnt vmcnt(10)" ::: "memory");                 \
        }                                                                     \
        asm volatile("s_waitcnt lgkmcnt(0)\n\ts_barrier" ::: "memory");       \
        h0f = *reinterpret_cast<const bf16x8*>(&hb[((u) + 1) & 1][rbase]);    \
        h1f = *reinterpret_cast<const bf16x8*>(&hb[((u) + 1) & 1][rbase + 32]); \
    } while (0)

    for (int tb = 0; tb < T_; tb += 8) {
        STEP(0, tb, pxA); STEP(1, tb, pxB);
        STEP(2, tb, pxA); STEP(3, tb, pxB);
        STEP(4, tb, pxA); STEP(5, tb, pxB);
        STEP(6, tb, pxA); STEP(7, tb, pxB);
    }
#undef STEP
#undef ISSUE

    // ---- epilogue: out[row][o] = h_last . W_out[o] + b_out[o] ----
    // All waves hold identical h_last frags; wave 0 does the output.
    if (w == 0) {
        float hf[16];
        {
            u32x4 H0 = __builtin_bit_cast(u32x4, h0f);
            u32x4 H1 = __builtin_bit_cast(u32x4, h1f);
#pragma unroll
            for (int p = 0; p < 4; ++p) {
                hf[2 * p]     = __builtin_bit_cast(float, H0[p] << 16);
                hf[2 * p + 1] = __builtin_bit_cast(float, H0[p] & 0xffff0000u);
                hf[8 + 2 * p]     = __builtin_bit_cast(float, H1[p] << 16);
                hf[8 + 2 * p + 1] = __builtin_bit_cast(float, H1[p] & 0xffff0000u);
            }
        }
        float pacc[O_];
#pragma unroll
        for (int o = 0; o < O_; ++o) {
            const float* wo = W_out + o * H_;
            float4 wA = *reinterpret_cast<const float4*>(wo + 8 * g);
            float4 wB = *reinterpret_cast<const float4*>(wo + 8 * g + 4);
            float4 wC = *reinterpret_cast<const float4*>(wo + 32 + 8 * g);
            float4 wD = *reinterpret_cast<const float4*>(wo + 32 + 8 * g + 4);
            float s = hf[0] * wA.x + hf[1] * wA.y + hf[2] * wA.z + hf[3] * wA.w
                    + hf[4] * wB.x + hf[5] * wB.y + hf[6] * wB.z + hf[7] * wB.w
                    + hf[8] * wC.x + hf[9] * wC.y + hf[10] * wC.z + hf[11] * wC.w
                    + hf[12] * wD.x + hf[13] * wD.y + hf[14] * wD.z + hf[15] * wD.w;
            s += __shfl_xor(s, 16);
            s += __shfl_xor(s, 32);
            pacc[o] = s;
        }
        if (g == 0) {
#pragma unroll
            for (int o = 0; o < O_; ++o)
                out[(size_t)row * O_ + o] = pacc[o] + b_out[o];
        }
    }
}

extern "C" void kernel_launch(void* const* d_in, const int* in_sizes, int n_in,
                              void* d_out, int out_size, void* d_ws, size_t ws_size,
                              hipStream_t stream) {
    const float* x     = (const float*)d_in[0];
    const float* W_ih  = (const float*)d_in[1];
    const float* W_hh  = (const float*)d_in[2];
    const float* b_ih  = (const float*)d_in[3];
    const float* b_hh  = (const float*)d_in[4];
    const float* W_out = (const float*)d_in[5];
    const float* b_out = (const float*)d_in[6];
    float* out = (float*)d_out;

    dim3 grid(B_ / 16);
    dim3 block(256);
    rnn_split_kernel<<<grid, block, 0, stream>>>(x, W_ih, W_hh, b_ih, b_hh,
                                                 W_out, b_out, out);
}